// Round 18
// baseline (205.251 us; speedup 1.0000x reference)
//
#include <hip/hip_runtime.h>
#include <math.h>

// Problem constants: B=8, L=1024, D_MODEL=512, H=8, DK=DV=64.

typedef __attribute__((ext_vector_type(4))) float f32x4;
typedef __attribute__((ext_vector_type(8))) __bf16 bf8;
typedef __attribute__((ext_vector_type(8))) unsigned short us8;
typedef __attribute__((ext_vector_type(4))) unsigned short us4;

#define LOG2E 1.44269504088896f

static __device__ __forceinline__ unsigned short f2bf(float f) {
  union { float f; unsigned u; } x; x.f = f;
  unsigned r = x.u + 0x7fffu + ((x.u >> 16) & 1u);   // RNE
  return (unsigned short)(r >> 16);
}

static __device__ __forceinline__ float bf2f(unsigned short u) {
  union { unsigned u; float f; } x; x.u = ((unsigned)u) << 16;
  return x.f;
}

static __device__ __forceinline__ f32x4 mfma16(bf8 a, bf8 b, f32x4 c) {
  return __builtin_amdgcn_mfma_f32_16x16x32_bf16(a, b, c, 0, 0, 0);
}

// ---------------- fused QKV projection (BK=32 -- R14 config) ----------------
// grid (64,4,3): z selects {q->QH, k->KH, v->VT}. 768 WGs coresident.
// R18: A-matrix (q/k/v) loads are NON-TEMPORAL -- single-use 50MB stream,
// don't evict W / other working set from L2.
// z<2: out [b][h][l][d] bf16 (Q scaled by log2e/8); z==2: out [b][h][d][l].
__global__ __launch_bounds__(256) void qkv_proj(
    const float* __restrict__ q, const float* __restrict__ k, const float* __restrict__ v,
    const float* __restrict__ wqW, const float* __restrict__ wkW, const float* __restrict__ wvW,
    const float* __restrict__ wqb, const float* __restrict__ wkb, const float* __restrict__ wvb,
    unsigned short* __restrict__ QH, unsigned short* __restrict__ KH,
    unsigned short* __restrict__ VT) {
  __shared__ __align__(16) unsigned short As[128 * 32];
  __shared__ __align__(16) unsigned short Bs[128 * 32];
  const int tid = threadIdx.x;
  const int lane = tid & 63, w = tid >> 6;
  const int lg = lane >> 4, ln = lane & 15;
  const int wr = w >> 1, wc = w & 1;
  const int bm = blockIdx.x, bn = blockIdx.y, z = blockIdx.z;

  const float* A    = (z == 0) ? q   : (z == 1) ? k   : v;
  const float* W    = (z == 0) ? wqW : (z == 1) ? wkW : wvW;
  const float* bias = (z == 0) ? wqb : (z == 1) ? wkb : wvb;
  unsigned short* outb = (z == 0) ? QH : (z == 1) ? KH : VT;
  const float scale = (z == 0) ? 0.125f * LOG2E : 1.f;

  f32x4 acc[4][4] = {};

  for (int kt = 0; kt < 16; ++kt) {
    const int k0 = kt * 32;
    f32x4 areg[4]; f32x4 breg[4];
#pragma unroll
    for (int i = 0; i < 4; ++i) {
      int e = i * 1024 + tid * 4;
      int r = e >> 5, c = e & 31;
      areg[i] = __builtin_nontemporal_load(
          (const f32x4*)(A + (size_t)(bm * 128 + r) * 512 + k0 + c));
      breg[i] = *(const f32x4*)(W + (size_t)(bn * 128 + r) * 512 + k0 + c);
    }
    __syncthreads();
#pragma unroll
    for (int i = 0; i < 4; ++i) {
      int e = i * 1024 + tid * 4;
      int r = e >> 5, c = e & 31;
      us4 ua, ub;
#pragma unroll
      for (int t = 0; t < 4; ++t) { ua[t] = f2bf(areg[i][t]); ub[t] = f2bf(breg[i][t]); }
      *(us4*)&As[r * 32 + c] = ua;
      *(us4*)&Bs[r * 32 + c] = ub;
    }
    __syncthreads();
    bf8 af[4], bfm[4];
#pragma unroll
    for (int m = 0; m < 4; ++m)
      af[m] = *(const bf8*)&As[(wr * 64 + m * 16 + ln) * 32 + lg * 8];
#pragma unroll
    for (int n = 0; n < 4; ++n)
      bfm[n] = *(const bf8*)&Bs[(wc * 64 + n * 16 + ln) * 32 + lg * 8];
#pragma unroll
    for (int m = 0; m < 4; ++m)
#pragma unroll
      for (int n = 0; n < 4; ++n)
        acc[m][n] = mfma16(af[m], bfm[n], acc[m][n]);
  }

#pragma unroll
  for (int m = 0; m < 4; ++m) {
#pragma unroll
    for (int n = 0; n < 4; ++n) {
      const int col = bn * 128 + wc * 64 + n * 16 + ln;
      const int row0 = bm * 128 + wr * 64 + m * 16 + lg * 4;
      const float bcol = bias[col];
#pragma unroll
      for (int r = 0; r < 4; ++r) {
        const int rg = row0 + r;
        const float val = (acc[m][n][r] + bcol) * scale;
        const int bb = rg >> 10, lq = rg & 1023, hh = col >> 6, dd = col & 63;
        if (z < 2)
          outb[((size_t)(bb * 8 + hh) * 1024 + lq) * 64 + dd] = f2bf(val);
        else
          outb[((size_t)(bb * 8 + hh) * 64 + dd) * 1024 + lq] = f2bf(val);
      }
    }
  }
}

// ---------------- fused attention (R14-verbatim) ----------------------------
// grid 2048: wgid = qblk*64 + bh -> XCD = bh&7 = h; K/V L2-resident, NT attn
// stores prevent L2 eviction (R11); batched-ILP loads (R12); V prefetch
// across the barrier + fused PV/store loop (R13); in-kernel posi (R14).
__global__ __launch_bounds__(512, 4) void attn_fused(
    const unsigned short* __restrict__ QH, const unsigned short* __restrict__ KH,
    const unsigned short* __restrict__ VT,
    const float* __restrict__ p0, const float* __restrict__ p1,
    const float* __restrict__ p2, const float* __restrict__ p3,
    float* __restrict__ attn_out, unsigned short* __restrict__ Omat) {
  __shared__ __align__(16) unsigned short pbuf[2][16][1048];  // 67 KB
  __shared__ float posi_w[1056];                              // 4.2 KB window
  __shared__ float lred[2][4][16];

  const int tid = threadIdx.x;
  const int lane = tid & 63, w = tid >> 6;
  const int lg = lane >> 4, ln = lane & 15;
  const int sp = w >> 2, kq = w & 3;            // kq doubles as dq in PV
  const int wgid = blockIdx.x;
  const int bh = wgid & 63, qblk = wgid >> 6;   // qblk in [0,32)
  const int b = bh >> 3, h = bh & 7;
  const int q0 = qblk * 32;

  // posi window computed in-kernel: local i <-> d = qi-kj = q0 + i - 1023.
  {
    const float p0h = p0[h], p1h = p1[h], p2h = p2[h], p3h = p3[h];
    const float sp1 = (p1h > 20.f) ? p1h : log1pf(expf(p1h));
    const float sp2 = (p2h > 20.f) ? p2h : log1pf(expf(p2h));
    for (int i = tid; i < 1056; i += 512) {
      const float d = (float)(q0 + i - 1023);
      const float s = fabsf(d);
      posi_w[i] = p0h * (expf(-sp1 * s) + expf(-sp2 * s) +
                         ((d < 0.f) ? p3h : 0.f)) * LOG2E;
    }
  }
  __syncthreads();

  const size_t base = (size_t)(b * 8 + h) * 1024 * 64;
  const unsigned short* Qb = QH + base;
  const unsigned short* Kb = KH + base;
  const unsigned short* Vb = VT + base;

  const int qrow = sp * 16 + ln;          // scores-layout row within WG
  const unsigned short* qr = Qb + (size_t)(q0 + qrow) * 64 + lg * 8;
  const bf8 bq0 = *(const bf8*)qr;
  const bf8 bq1 = *(const bf8*)(qr + 32);

  // ---- PASS 1: P production over this wave's kj quarter (256 kj) ----
  const int kbase = kq << 8;
  f32x4 laccv = {0.f, 0.f, 0.f, 0.f};
#pragma unroll
  for (int kt = 0; kt < 4; ++kt) {
    const int k0 = kbase + kt * 64;
    bf8 ka[4][2];
#pragma unroll
    for (int n = 0; n < 4; ++n) {
      const unsigned short* kr = Kb + (size_t)(k0 + n * 16 + ln) * 64 + lg * 8;
      ka[n][0] = *(const bf8*)kr;
      ka[n][1] = *(const bf8*)(kr + 32);
    }
#pragma unroll
    for (int n = 0; n < 4; ++n) {
      f32x4 sc = {};
      sc = mfma16(ka[n][0], bq0, sc);
      sc = mfma16(ka[n][1], bq1, sc);
      const int kjb = k0 + n * 16 + lg * 4;        // kj of reg r = kjb + r
      const int pli = qrow - kjb + 1023;           // posi_w idx for r = pli - r
      us4 pb;
#pragma unroll
      for (int r = 0; r < 4; ++r) {
        float p = exp2f(sc[r] + posi_w[pli - r]);
        laccv[r] += p;
        pb[r] = f2bf(p);
      }
      *(us4*)&pbuf[sp][ln][kjb] = pb;              // ds_write_b64, chain ends
    }
  }
  float lacc = laccv[0] + laccv[1] + laccv[2] + laccv[3];
  lacc += __shfl_xor(lacc, 16, 64);
  lacc += __shfl_xor(lacc, 32, 64);
  if (lg == 0) lred[sp][kq][ln] = lacc;

  // V group-0 prefetch: independent of the barrier -- issue NOW.
  const unsigned short* vrow = Vb + (size_t)(kq * 16 + ln) * 1024;
  bf8 va[4][2];
#pragma unroll
  for (int j = 0; j < 4; ++j) {
    va[j][0] = *(const bf8*)(vrow + j * 64 + lg * 8);
    va[j][1] = *(const bf8*)(vrow + j * 64 + 32 + lg * 8);
  }

  __syncthreads();                                  // P + lred complete

  // Hoist all 16 row reciprocals (uniform across the wave's lanes).
  float rl[16];
#pragma unroll
  for (int r = 0; r < 16; ++r)
    rl[r] = 1.f / (lred[sp][0][r] + lred[sp][1][r] +
                   lred[sp][2][r] + lred[sp][3][r]);

  // ---- fused PV + attn store: 16 iters, kt <-> store row r=kt ----
  f32x4 oacc = {};
  float* abb = attn_out + (size_t)(h * 8 + b) * 1024 * 1024;
#pragma unroll
  for (int g = 0; g < 4; ++g) {
    bf8 vn[4][2];
    if (g < 3) {
#pragma unroll
      for (int j = 0; j < 4; ++j) {
        const int k0 = (g + 1) * 256 + j * 64;
        vn[j][0] = *(const bf8*)(vrow + k0 + lg * 8);
        vn[j][1] = *(const bf8*)(vrow + k0 + 32 + lg * 8);
      }
    }
#pragma unroll
    for (int j = 0; j < 4; ++j) {
      const int kt = g * 4 + j;
      const int k0 = kt * 64;
      // PV slice
      const bf8 pa0 = *(const bf8*)&pbuf[sp][ln][k0 + lg * 8];
      const bf8 pa1 = *(const bf8*)&pbuf[sp][ln][k0 + 32 + lg * 8];
      oacc = mfma16(pa0, va[j][0], oacc);
      oacc = mfma16(pa1, va[j][1], oacc);
      // store row kt (interleaved with MFMA; disjoint pipes)
      us4 pv = *(const us4*)&pbuf[sp][kt][kq * 256 + lane * 4];
      f32x4 f0;
#pragma unroll
      for (int t = 0; t < 4; ++t) f0[t] = bf2f(pv[t]) * rl[kt];
      __builtin_nontemporal_store(
          f0, (f32x4*)(abb + (size_t)(q0 + sp * 16 + kt) * 1024 + kq * 256 + lane * 4));
    }
#pragma unroll
    for (int j = 0; j < 4; ++j) { va[j][0] = vn[j][0]; va[j][1] = vn[j][1]; }
  }

  // O fragment rows are lg*4+r: normalize per-register with that row's sum.
#pragma unroll
  for (int r = 0; r < 4; ++r) {
    const int row = lg * 4 + r;
    Omat[(size_t)(b * 1024 + q0 + sp * 16 + row) * 512 +
         h * 64 + kq * 16 + ln] = f2bf(oacc[r] * rl[row]);
  }
}

// ---------------- fused fc + residual + LayerNorm --------------------------
// grid 256: bm -> rows [bm*32, bm*32+32). 512 threads = 8 waves.
// Tile 32x512 (FULL rows per WG => LN fuses). Wave w: mh = w&1, nc = w>>1.
// acc[nf] reg r: row = mh*16 + lg*4 + r, col = nc*128 + nf*16 + ln.
// R18: resid load NT (q stream, won't be L2-resident anyway); out store NT
// (never re-read on device).
__global__ __launch_bounds__(512, 4) void gemm_fc_ln(
    const unsigned short* __restrict__ Ap, const float* __restrict__ W,
    const float* __restrict__ bias, const float* __restrict__ resid,
    const float* __restrict__ lng, const float* __restrict__ lnb,
    float* __restrict__ out) {
  __shared__ __align__(16) unsigned short As[32 * 32];    //  2 KB
  __shared__ __align__(16) unsigned short Bs[512 * 32];   // 32 KB
  __shared__ float lsum[4][32], lsq[4][32];
  __shared__ float murs[32][2];

  const int tid = threadIdx.x;
  const int lane = tid & 63, w = tid >> 6;
  const int lg = lane >> 4, ln = lane & 15;
  const int mh = w & 1, nc = w >> 1;
  const int bm = blockIdx.x;

  f32x4 acc[8] = {};

  for (int kt = 0; kt < 16; ++kt) {
    const int k0 = kt * 32;
    us8 areg; f32x4 breg[8];
    if (tid < 128) {
      int r = tid >> 2, c8 = (tid & 3) * 8;
      areg = *(const us8*)(Ap + (size_t)(bm * 32 + r) * 512 + k0 + c8);
    }
#pragma unroll
    for (int i = 0; i < 8; ++i) {
      int e = i * 2048 + tid * 4;
      int r = e >> 5, c = e & 31;
      breg[i] = *(const f32x4*)(W + (size_t)r * 512 + k0 + c);
    }
    __syncthreads();
    if (tid < 128) {
      int r = tid >> 2, c8 = (tid & 3) * 8;
      *(us8*)&As[r * 32 + c8] = areg;
    }
#pragma unroll
    for (int i = 0; i < 8; ++i) {
      int e = i * 2048 + tid * 4;
      int r = e >> 5, c = e & 31;
      us4 u;
#pragma unroll
      for (int t = 0; t < 4; ++t) u[t] = f2bf(breg[i][t]);
      *(us4*)&Bs[r * 32 + c] = u;
    }
    __syncthreads();
    const bf8 af = *(const bf8*)&As[(mh * 16 + ln) * 32 + lg * 8];
#pragma unroll
    for (int nf = 0; nf < 8; ++nf) {
      const bf8 bf = *(const bf8*)&Bs[(nc * 128 + nf * 16 + ln) * 32 + lg * 8];
      acc[nf] = mfma16(af, bf, acc[nf]);
    }
  }

  // ---- epilogue: + bias + resid, then fused LN ----
  float bcol[8];
#pragma unroll
  for (int nf = 0; nf < 8; ++nf) bcol[nf] = bias[nc * 128 + nf * 16 + ln];
#pragma unroll
  for (int nf = 0; nf < 8; ++nf) {
    const int col = nc * 128 + nf * 16 + ln;
#pragma unroll
    for (int r = 0; r < 4; ++r) {
      const int rg = bm * 32 + mh * 16 + lg * 4 + r;
      acc[nf][r] += bcol[nf] +
          __builtin_nontemporal_load(resid + (size_t)rg * 512 + col);
    }
  }
#pragma unroll
  for (int r = 0; r < 4; ++r) {
    float ps = 0.f, pq = 0.f;
#pragma unroll
    for (int nf = 0; nf < 8; ++nf) { ps += acc[nf][r]; pq += acc[nf][r] * acc[nf][r]; }
#pragma unroll
    for (int msk = 1; msk <= 8; msk <<= 1) {
      ps += __shfl_xor(ps, msk, 64);
      pq += __shfl_xor(pq, msk, 64);
    }
    if (ln == 0) {
      lsum[nc][mh * 16 + lg * 4 + r] = ps;
      lsq[nc][mh * 16 + lg * 4 + r] = pq;
    }
  }
  __syncthreads();
  if (tid < 32) {
    const float s = lsum[0][tid] + lsum[1][tid] + lsum[2][tid] + lsum[3][tid];
    const float q = lsq[0][tid] + lsq[1][tid] + lsq[2][tid] + lsq[3][tid];
    const float mu = s * (1.f / 512.f);
    const float var = q * (1.f / 512.f) - mu * mu;
    murs[tid][0] = mu;
    murs[tid][1] = rsqrtf(var + 1e-5f);
  }
  __syncthreads();
#pragma unroll
  for (int nf = 0; nf < 8; ++nf) {
    const int col = nc * 128 + nf * 16 + ln;
    const float gc = lng[col], bc = lnb[col];
#pragma unroll
    for (int r = 0; r < 4; ++r) {
      const int tr = mh * 16 + lg * 4 + r;
      const int rg = bm * 32 + tr;
      __builtin_nontemporal_store(
          (acc[nf][r] - murs[tr][0]) * murs[tr][1] * gc + bc,
          out + (size_t)rg * 512 + col);
    }
  }
}

extern "C" void kernel_launch(void* const* d_in, const int* in_sizes, int n_in,
                              void* d_out, int out_size, void* d_ws, size_t ws_size,
                              hipStream_t stream) {
  const float* q   = (const float*)d_in[0];
  const float* k   = (const float*)d_in[1];
  const float* v   = (const float*)d_in[2];
  const float* wqW = (const float*)d_in[3];
  const float* wqb = (const float*)d_in[4];
  const float* wkW = (const float*)d_in[5];
  const float* wkb = (const float*)d_in[6];
  const float* wvW = (const float*)d_in[7];
  const float* wvb = (const float*)d_in[8];
  const float* fcW = (const float*)d_in[9];
  const float* fcb = (const float*)d_in[10];
  const float* lng = (const float*)d_in[11];
  const float* lnb = (const float*)d_in[12];
  const float* p0  = (const float*)d_in[13];
  const float* p1  = (const float*)d_in[14];
  const float* p2  = (const float*)d_in[15];
  const float* p3  = (const float*)d_in[16];

  char* ws = (char*)d_ws;
  unsigned short* QH   = (unsigned short*)(ws);              //  8 MiB  [b][h][l][64]
  unsigned short* KH   = (unsigned short*)(ws + 8388608);    //  8 MiB  [b][h][l][64]
  unsigned short* VT   = (unsigned short*)(ws + 16777216);   //  8 MiB  [b][h][64][l]
  unsigned short* Omat = (unsigned short*)(ws + 25165824);   //  8 MiB  [b*l][512]

  float* out0 = (float*)d_out;
  float* attn = out0 + (size_t)8 * 1024 * 512;

  qkv_proj<<<dim3(64, 4, 3), 256, 0, stream>>>(q, k, v, wqW, wkW, wvW,
                                               wqb, wkb, wvb, QH, KH, VT);
  attn_fused<<<2048, 512, 0, stream>>>(QH, KH, VT, p0, p1, p2, p3, attn, Omat);
  gemm_fc_ln<<<256, 512, 0, stream>>>(Omat, fcW, fcb, q, lng, lnb, out0);
}

// Round 19
// 195.692 us; speedup vs baseline: 1.0488x; 1.0488x over previous
//
#include <hip/hip_runtime.h>
#include <math.h>

// Problem constants: B=8, L=1024, D_MODEL=512, H=8, DK=DV=64.

typedef __attribute__((ext_vector_type(4))) float f32x4;
typedef __attribute__((ext_vector_type(8))) __bf16 bf8;
typedef __attribute__((ext_vector_type(8))) unsigned short us8;
typedef __attribute__((ext_vector_type(4))) unsigned short us4;

#define LOG2E 1.44269504088896f

static __device__ __forceinline__ unsigned short f2bf(float f) {
  union { float f; unsigned u; } x; x.f = f;
  unsigned r = x.u + 0x7fffu + ((x.u >> 16) & 1u);   // RNE
  return (unsigned short)(r >> 16);
}

static __device__ __forceinline__ float bf2f(unsigned short u) {
  union { unsigned u; float f; } x; x.u = ((unsigned)u) << 16;
  return x.f;
}

static __device__ __forceinline__ f32x4 mfma16(bf8 a, bf8 b, f32x4 c) {
  return __builtin_amdgcn_mfma_f32_16x16x32_bf16(a, b, c, 0, 0, 0);
}

// ---------------- fused QKV projection (BK=32 -- R14/R17 config) ------------
// grid (64,4,3): z selects {q->QH, k->KH, v->VT}. 768 WGs coresident.
// R18's NT loads on A REVERTED: each A-tile is reused by 4 bn-WGs; NT
// defeated that L2 reuse (~150MB extra HBM read, -9us).
// z<2: out [b][h][l][d] bf16 (Q scaled by log2e/8); z==2: out [b][h][d][l].
__global__ __launch_bounds__(256) void qkv_proj(
    const float* __restrict__ q, const float* __restrict__ k, const float* __restrict__ v,
    const float* __restrict__ wqW, const float* __restrict__ wkW, const float* __restrict__ wvW,
    const float* __restrict__ wqb, const float* __restrict__ wkb, const float* __restrict__ wvb,
    unsigned short* __restrict__ QH, unsigned short* __restrict__ KH,
    unsigned short* __restrict__ VT) {
  __shared__ __align__(16) unsigned short As[128 * 32];
  __shared__ __align__(16) unsigned short Bs[128 * 32];
  const int tid = threadIdx.x;
  const int lane = tid & 63, w = tid >> 6;
  const int lg = lane >> 4, ln = lane & 15;
  const int wr = w >> 1, wc = w & 1;
  const int bm = blockIdx.x, bn = blockIdx.y, z = blockIdx.z;

  const float* A    = (z == 0) ? q   : (z == 1) ? k   : v;
  const float* W    = (z == 0) ? wqW : (z == 1) ? wkW : wvW;
  const float* bias = (z == 0) ? wqb : (z == 1) ? wkb : wvb;
  unsigned short* outb = (z == 0) ? QH : (z == 1) ? KH : VT;
  const float scale = (z == 0) ? 0.125f * LOG2E : 1.f;

  f32x4 acc[4][4] = {};

  for (int kt = 0; kt < 16; ++kt) {
    const int k0 = kt * 32;
    f32x4 areg[4]; f32x4 breg[4];
#pragma unroll
    for (int i = 0; i < 4; ++i) {
      int e = i * 1024 + tid * 4;
      int r = e >> 5, c = e & 31;
      areg[i] = *(const f32x4*)(A + (size_t)(bm * 128 + r) * 512 + k0 + c);
      breg[i] = *(const f32x4*)(W + (size_t)(bn * 128 + r) * 512 + k0 + c);
    }
    __syncthreads();
#pragma unroll
    for (int i = 0; i < 4; ++i) {
      int e = i * 1024 + tid * 4;
      int r = e >> 5, c = e & 31;
      us4 ua, ub;
#pragma unroll
      for (int t = 0; t < 4; ++t) { ua[t] = f2bf(areg[i][t]); ub[t] = f2bf(breg[i][t]); }
      *(us4*)&As[r * 32 + c] = ua;
      *(us4*)&Bs[r * 32 + c] = ub;
    }
    __syncthreads();
    bf8 af[4], bfm[4];
#pragma unroll
    for (int m = 0; m < 4; ++m)
      af[m] = *(const bf8*)&As[(wr * 64 + m * 16 + ln) * 32 + lg * 8];
#pragma unroll
    for (int n = 0; n < 4; ++n)
      bfm[n] = *(const bf8*)&Bs[(wc * 64 + n * 16 + ln) * 32 + lg * 8];
#pragma unroll
    for (int m = 0; m < 4; ++m)
#pragma unroll
      for (int n = 0; n < 4; ++n)
        acc[m][n] = mfma16(af[m], bfm[n], acc[m][n]);
  }

#pragma unroll
  for (int m = 0; m < 4; ++m) {
#pragma unroll
    for (int n = 0; n < 4; ++n) {
      const int col = bn * 128 + wc * 64 + n * 16 + ln;
      const int row0 = bm * 128 + wr * 64 + m * 16 + lg * 4;
      const float bcol = bias[col];
#pragma unroll
      for (int r = 0; r < 4; ++r) {
        const int rg = row0 + r;
        const float val = (acc[m][n][r] + bcol) * scale;
        const int bb = rg >> 10, lq = rg & 1023, hh = col >> 6, dd = col & 63;
        if (z < 2)
          outb[((size_t)(bb * 8 + hh) * 1024 + lq) * 64 + dd] = f2bf(val);
        else
          outb[((size_t)(bb * 8 + hh) * 64 + dd) * 1024 + lq] = f2bf(val);
      }
    }
  }
}

// ---------------- fused attention (R14-verbatim) ----------------------------
// grid 2048: wgid = qblk*64 + bh -> XCD = bh&7 = h; K/V L2-resident, NT attn
// stores prevent L2 eviction (R11); batched-ILP loads (R12); V prefetch
// across the barrier + fused PV/store loop (R13); in-kernel posi (R14).
__global__ __launch_bounds__(512, 4) void attn_fused(
    const unsigned short* __restrict__ QH, const unsigned short* __restrict__ KH,
    const unsigned short* __restrict__ VT,
    const float* __restrict__ p0, const float* __restrict__ p1,
    const float* __restrict__ p2, const float* __restrict__ p3,
    float* __restrict__ attn_out, unsigned short* __restrict__ Omat) {
  __shared__ __align__(16) unsigned short pbuf[2][16][1048];  // 67 KB
  __shared__ float posi_w[1056];                              // 4.2 KB window
  __shared__ float lred[2][4][16];

  const int tid = threadIdx.x;
  const int lane = tid & 63, w = tid >> 6;
  const int lg = lane >> 4, ln = lane & 15;
  const int sp = w >> 2, kq = w & 3;            // kq doubles as dq in PV
  const int wgid = blockIdx.x;
  const int bh = wgid & 63, qblk = wgid >> 6;   // qblk in [0,32)
  const int b = bh >> 3, h = bh & 7;
  const int q0 = qblk * 32;

  // posi window computed in-kernel: local i <-> d = qi-kj = q0 + i - 1023.
  {
    const float p0h = p0[h], p1h = p1[h], p2h = p2[h], p3h = p3[h];
    const float sp1 = (p1h > 20.f) ? p1h : log1pf(expf(p1h));
    const float sp2 = (p2h > 20.f) ? p2h : log1pf(expf(p2h));
    for (int i = tid; i < 1056; i += 512) {
      const float d = (float)(q0 + i - 1023);
      const float s = fabsf(d);
      posi_w[i] = p0h * (expf(-sp1 * s) + expf(-sp2 * s) +
                         ((d < 0.f) ? p3h : 0.f)) * LOG2E;
    }
  }
  __syncthreads();

  const size_t base = (size_t)(b * 8 + h) * 1024 * 64;
  const unsigned short* Qb = QH + base;
  const unsigned short* Kb = KH + base;
  const unsigned short* Vb = VT + base;

  const int qrow = sp * 16 + ln;          // scores-layout row within WG
  const unsigned short* qr = Qb + (size_t)(q0 + qrow) * 64 + lg * 8;
  const bf8 bq0 = *(const bf8*)qr;
  const bf8 bq1 = *(const bf8*)(qr + 32);

  // ---- PASS 1: P production over this wave's kj quarter (256 kj) ----
  const int kbase = kq << 8;
  f32x4 laccv = {0.f, 0.f, 0.f, 0.f};
#pragma unroll
  for (int kt = 0; kt < 4; ++kt) {
    const int k0 = kbase + kt * 64;
    bf8 ka[4][2];
#pragma unroll
    for (int n = 0; n < 4; ++n) {
      const unsigned short* kr = Kb + (size_t)(k0 + n * 16 + ln) * 64 + lg * 8;
      ka[n][0] = *(const bf8*)kr;
      ka[n][1] = *(const bf8*)(kr + 32);
    }
#pragma unroll
    for (int n = 0; n < 4; ++n) {
      f32x4 sc = {};
      sc = mfma16(ka[n][0], bq0, sc);
      sc = mfma16(ka[n][1], bq1, sc);
      const int kjb = k0 + n * 16 + lg * 4;        // kj of reg r = kjb + r
      const int pli = qrow - kjb + 1023;           // posi_w idx for r = pli - r
      us4 pb;
#pragma unroll
      for (int r = 0; r < 4; ++r) {
        float p = exp2f(sc[r] + posi_w[pli - r]);
        laccv[r] += p;
        pb[r] = f2bf(p);
      }
      *(us4*)&pbuf[sp][ln][kjb] = pb;              // ds_write_b64, chain ends
    }
  }
  float lacc = laccv[0] + laccv[1] + laccv[2] + laccv[3];
  lacc += __shfl_xor(lacc, 16, 64);
  lacc += __shfl_xor(lacc, 32, 64);
  if (lg == 0) lred[sp][kq][ln] = lacc;

  // V group-0 prefetch: independent of the barrier -- issue NOW.
  const unsigned short* vrow = Vb + (size_t)(kq * 16 + ln) * 1024;
  bf8 va[4][2];
#pragma unroll
  for (int j = 0; j < 4; ++j) {
    va[j][0] = *(const bf8*)(vrow + j * 64 + lg * 8);
    va[j][1] = *(const bf8*)(vrow + j * 64 + 32 + lg * 8);
  }

  __syncthreads();                                  // P + lred complete

  // Hoist all 16 row reciprocals (uniform across the wave's lanes).
  float rl[16];
#pragma unroll
  for (int r = 0; r < 16; ++r)
    rl[r] = 1.f / (lred[sp][0][r] + lred[sp][1][r] +
                   lred[sp][2][r] + lred[sp][3][r]);

  // ---- fused PV + attn store: 16 iters, kt <-> store row r=kt ----
  f32x4 oacc = {};
  float* abb = attn_out + (size_t)(h * 8 + b) * 1024 * 1024;
#pragma unroll
  for (int g = 0; g < 4; ++g) {
    bf8 vn[4][2];
    if (g < 3) {
#pragma unroll
      for (int j = 0; j < 4; ++j) {
        const int k0 = (g + 1) * 256 + j * 64;
        vn[j][0] = *(const bf8*)(vrow + k0 + lg * 8);
        vn[j][1] = *(const bf8*)(vrow + k0 + 32 + lg * 8);
      }
    }
#pragma unroll
    for (int j = 0; j < 4; ++j) {
      const int kt = g * 4 + j;
      const int k0 = kt * 64;
      // PV slice
      const bf8 pa0 = *(const bf8*)&pbuf[sp][ln][k0 + lg * 8];
      const bf8 pa1 = *(const bf8*)&pbuf[sp][ln][k0 + 32 + lg * 8];
      oacc = mfma16(pa0, va[j][0], oacc);
      oacc = mfma16(pa1, va[j][1], oacc);
      // store row kt (interleaved with MFMA; disjoint pipes)
      us4 pv = *(const us4*)&pbuf[sp][kt][kq * 256 + lane * 4];
      f32x4 f0;
#pragma unroll
      for (int t = 0; t < 4; ++t) f0[t] = bf2f(pv[t]) * rl[kt];
      __builtin_nontemporal_store(
          f0, (f32x4*)(abb + (size_t)(q0 + sp * 16 + kt) * 1024 + kq * 256 + lane * 4));
    }
#pragma unroll
    for (int j = 0; j < 4; ++j) { va[j][0] = vn[j][0]; va[j][1] = vn[j][1]; }
  }

  // O fragment rows are lg*4+r: normalize per-register with that row's sum.
#pragma unroll
  for (int r = 0; r < 4; ++r) {
    const int row = lg * 4 + r;
    Omat[(size_t)(b * 1024 + q0 + sp * 16 + row) * 512 +
         h * 64 + kq * 16 + ln] = f2bf(oacc[r] * rl[row]);
  }
}

// ---------------- fused fc + residual + LayerNorm --------------------------
// grid 256: bm -> rows [bm*32, bm*32+32). 512 threads = 8 waves.
// Tile 32x512 (FULL rows per WG => LN fuses). Wave w: mh = w&1, nc = w>>1.
// acc[nf] reg r: row = mh*16 + lg*4 + r, col = nc*128 + nf*16 + ln.
__global__ __launch_bounds__(512, 4) void gemm_fc_ln(
    const unsigned short* __restrict__ Ap, const float* __restrict__ W,
    const float* __restrict__ bias, const float* __restrict__ resid,
    const float* __restrict__ lng, const float* __restrict__ lnb,
    float* __restrict__ out) {
  __shared__ __align__(16) unsigned short As[32 * 32];    //  2 KB
  __shared__ __align__(16) unsigned short Bs[512 * 32];   // 32 KB
  __shared__ float lsum[4][32], lsq[4][32];
  __shared__ float murs[32][2];

  const int tid = threadIdx.x;
  const int lane = tid & 63, w = tid >> 6;
  const int lg = lane >> 4, ln = lane & 15;
  const int mh = w & 1, nc = w >> 1;
  const int bm = blockIdx.x;

  f32x4 acc[8] = {};

  for (int kt = 0; kt < 16; ++kt) {
    const int k0 = kt * 32;
    us8 areg; f32x4 breg[8];
    if (tid < 128) {
      int r = tid >> 2, c8 = (tid & 3) * 8;
      areg = *(const us8*)(Ap + (size_t)(bm * 32 + r) * 512 + k0 + c8);
    }
#pragma unroll
    for (int i = 0; i < 8; ++i) {
      int e = i * 2048 + tid * 4;
      int r = e >> 5, c = e & 31;
      breg[i] = *(const f32x4*)(W + (size_t)r * 512 + k0 + c);
    }
    __syncthreads();
    if (tid < 128) {
      int r = tid >> 2, c8 = (tid & 3) * 8;
      *(us8*)&As[r * 32 + c8] = areg;
    }
#pragma unroll
    for (int i = 0; i < 8; ++i) {
      int e = i * 2048 + tid * 4;
      int r = e >> 5, c = e & 31;
      us4 u;
#pragma unroll
      for (int t = 0; t < 4; ++t) u[t] = f2bf(breg[i][t]);
      *(us4*)&Bs[r * 32 + c] = u;
    }
    __syncthreads();
    const bf8 af = *(const bf8*)&As[(mh * 16 + ln) * 32 + lg * 8];
#pragma unroll
    for (int nf = 0; nf < 8; ++nf) {
      const bf8 bf = *(const bf8*)&Bs[(nc * 128 + nf * 16 + ln) * 32 + lg * 8];
      acc[nf] = mfma16(af, bf, acc[nf]);
    }
  }

  // ---- epilogue: + bias + resid, then fused LN ----
  float bcol[8];
#pragma unroll
  for (int nf = 0; nf < 8; ++nf) bcol[nf] = bias[nc * 128 + nf * 16 + ln];
#pragma unroll
  for (int nf = 0; nf < 8; ++nf) {
    const int col = nc * 128 + nf * 16 + ln;
#pragma unroll
    for (int r = 0; r < 4; ++r) {
      const int rg = bm * 32 + mh * 16 + lg * 4 + r;
      acc[nf][r] += bcol[nf] + resid[(size_t)rg * 512 + col];
    }
  }
#pragma unroll
  for (int r = 0; r < 4; ++r) {
    float ps = 0.f, pq = 0.f;
#pragma unroll
    for (int nf = 0; nf < 8; ++nf) { ps += acc[nf][r]; pq += acc[nf][r] * acc[nf][r]; }
#pragma unroll
    for (int msk = 1; msk <= 8; msk <<= 1) {
      ps += __shfl_xor(ps, msk, 64);
      pq += __shfl_xor(pq, msk, 64);
    }
    if (ln == 0) {
      lsum[nc][mh * 16 + lg * 4 + r] = ps;
      lsq[nc][mh * 16 + lg * 4 + r] = pq;
    }
  }
  __syncthreads();
  if (tid < 32) {
    const float s = lsum[0][tid] + lsum[1][tid] + lsum[2][tid] + lsum[3][tid];
    const float q = lsq[0][tid] + lsq[1][tid] + lsq[2][tid] + lsq[3][tid];
    const float mu = s * (1.f / 512.f);
    const float var = q * (1.f / 512.f) - mu * mu;
    murs[tid][0] = mu;
    murs[tid][1] = rsqrtf(var + 1e-5f);
  }
  __syncthreads();
#pragma unroll
  for (int nf = 0; nf < 8; ++nf) {
    const int col = nc * 128 + nf * 16 + ln;
    const float gc = lng[col], bc = lnb[col];
#pragma unroll
    for (int r = 0; r < 4; ++r) {
      const int tr = mh * 16 + lg * 4 + r;
      const int rg = bm * 32 + tr;
      out[(size_t)rg * 512 + col] =
          (acc[nf][r] - murs[tr][0]) * murs[tr][1] * gc + bc;
    }
  }
}

extern "C" void kernel_launch(void* const* d_in, const int* in_sizes, int n_in,
                              void* d_out, int out_size, void* d_ws, size_t ws_size,
                              hipStream_t stream) {
  const float* q   = (const float*)d_in[0];
  const float* k   = (const float*)d_in[1];
  const float* v   = (const float*)d_in[2];
  const float* wqW = (const float*)d_in[3];
  const float* wqb = (const float*)d_in[4];
  const float* wkW = (const float*)d_in[5];
  const float* wkb = (const float*)d_in[6];
  const float* wvW = (const float*)d_in[7];
  const float* wvb = (const float*)d_in[8];
  const float* fcW = (const float*)d_in[9];
  const float* fcb = (const float*)d_in[10];
  const float* lng = (const float*)d_in[11];
  const float* lnb = (const float*)d_in[12];
  const float* p0  = (const float*)d_in[13];
  const float* p1  = (const float*)d_in[14];
  const float* p2  = (const float*)d_in[15];
  const float* p3  = (const float*)d_in[16];

  char* ws = (char*)d_ws;
  unsigned short* QH   = (unsigned short*)(ws);              //  8 MiB  [b][h][l][64]
  unsigned short* KH   = (unsigned short*)(ws + 8388608);    //  8 MiB  [b][h][l][64]
  unsigned short* VT   = (unsigned short*)(ws + 16777216);   //  8 MiB  [b][h][64][l]
  unsigned short* Omat = (unsigned short*)(ws + 25165824);   //  8 MiB  [b*l][512]

  float* out0 = (float*)d_out;
  float* attn = out0 + (size_t)8 * 1024 * 512;

  qkv_proj<<<dim3(64, 4, 3), 256, 0, stream>>>(q, k, v, wqW, wkW, wvW,
                                               wqb, wkb, wvb, QH, KH, VT);
  attn_fused<<<2048, 512, 0, stream>>>(QH, KH, VT, p0, p1, p2, p3, attn, Omat);
  gemm_fc_ln<<<256, 512, 0, stream>>>(Omat, fcW, fcb, q, lng, lnb, out0);
}